// Round 1
// 633.860 us; speedup vs baseline: 1.0331x; 1.0331x over previous
//
#include <hip/hip_runtime.h>

typedef __attribute__((ext_vector_type(4))) float f32x4;
typedef __attribute__((ext_vector_type(8))) __bf16 bf16x8;

#define MFMA(a, b, c) __builtin_amdgcn_mfma_f32_16x16x32_bf16(a, b, c, 0, 0, 0)

// Zero-cost ordering for wave-private LDS round-trips: compiler fence + wave
// scheduling barrier. HW DS pipe services a wave's LDS ops in order.
__device__ __forceinline__ void wave_fence() {
  asm volatile("" ::: "memory");
  __builtin_amdgcn_wave_barrier();
  asm volatile("" ::: "memory");
}

__device__ __forceinline__ bf16x8 pack8(f32x4 a, f32x4 b) {
  bf16x8 r;
  r[0] = (__bf16)a[0]; r[1] = (__bf16)a[1]; r[2] = (__bf16)a[2]; r[3] = (__bf16)a[3];
  r[4] = (__bf16)b[0]; r[5] = (__bf16)b[1]; r[6] = (__bf16)b[2]; r[7] = (__bf16)b[3];
  return r;
}

constexpr int SD  = 262144;   // S*D
constexpr int HSD = 4194304;  // H*S*D

// LDS layout (__bf16 elements):
//  [0,4096)       Wq B-fragments, tile t = kt*4+nt, elem = t*512 + lane*8 + j
//  [4096,8192)    Wk
//  [8192,12288)   Wv
//  [12288,20480)  W1 B-fragments, tile t = kt*8+nt
//  [20480,28672)  W2 B-fragments, tile t = kt*4+nt  (moved out of VGPRs to pay
//                 for the software-pipeline prefetch registers)
//  [28672,32768)  per-wave A-staging [16][64], XOR-swizzled:
//                 phys = m*64 + (((k>>3)^(m&7))<<3) + (k&7)
__global__ __launch_bounds__(256, 2) void mixer_kernel(
    const float* __restrict__ Qg, const float* __restrict__ Kg,
    const float* __restrict__ Vg, const float* __restrict__ Mg,
    const float* __restrict__ Wq, const float* __restrict__ Wk,
    const float* __restrict__ Wv, const float* __restrict__ FG,
    const float* __restrict__ L1W, const float* __restrict__ L1B,
    const float* __restrict__ W1, const float* __restrict__ L2W,
    const float* __restrict__ L2B, const float* __restrict__ W2,
    const float* __restrict__ B2g, float* __restrict__ Out,
    float* __restrict__ Cm) {
  __shared__ __attribute__((aligned(16))) __bf16 lds[32768];
  const int tid = threadIdx.x;
  const int wave = tid >> 6, lane = tid & 63;
  const int c = lane & 15, g = lane >> 4;
  const int aoff = c * 64 + g * 8;      // A-frag: m=c(token/head), k=g*8+j
  const int p0 = blockIdx.x * 32;

  // ---- prologue: issue it=0 global loads FIRST so HBM latency hides under
  //      weight staging ----
  int pair = p0 + wave;                 // (b,s) flat index for it=0
  f32x4 q0, q1, q2, q3, k0, k1, k2, k3, v0, v1, v2, v3;
  float mv[4][4];
  int mb;
  {
    const float* qp = Qg + pair * 1024;
    const float* kp = Kg + pair * 1024;
    const float* vp = Vg + pair * 1024;
    q0 = *(const f32x4*)(qp + aoff);      q1 = *(const f32x4*)(qp + aoff + 4);
    q2 = *(const f32x4*)(qp + aoff + 32); q3 = *(const f32x4*)(qp + aoff + 36);
    k0 = *(const f32x4*)(kp + aoff);      k1 = *(const f32x4*)(kp + aoff + 4);
    k2 = *(const f32x4*)(kp + aoff + 32); k3 = *(const f32x4*)(kp + aoff + 36);
    v0 = *(const f32x4*)(vp + aoff);      v1 = *(const f32x4*)(vp + aoff + 4);
    v2 = *(const f32x4*)(vp + aoff + 32); v3 = *(const f32x4*)(vp + aoff + 36);
    mb = (pair >> 12) * HSD + (pair & 4095) * 64 + c;
#pragma unroll
    for (int nt = 0; nt < 4; ++nt)
#pragma unroll
      for (int r = 0; r < 4; ++r)
        mv[nt][r] = Mg[mb + (g * 4 + r) * SD + nt * 16];
  }

  // ---- stage weight B-fragments (fragment-major bf16) ----
  for (int i = tid; i < 4096; i += 256) {
    const int j = i & 7, L = (i >> 3) & 63, t = i >> 9;        // t = kt*4+nt
    const int k = ((t >> 2) << 5) + ((L >> 4) << 3) + j;        // d index
    const int n = ((t & 3) << 4) + (L & 15);                    // e index
    lds[i]         = (__bf16)Wq[n * 64 + k];
    lds[4096 + i]  = (__bf16)Wk[n * 64 + k];
    lds[8192 + i]  = (__bf16)Wv[n * 64 + k];
  }
  for (int i = tid; i < 8192; i += 256) {
    const int j = i & 7, L = (i >> 3) & 63, t = i >> 9;
    // W1: t = kt*8+nt (kt in 0..1, nt in 0..7), W1 is [2D=128][D=64]
    const int k1 = ((t >> 3) << 5) + ((L >> 4) << 3) + j;
    const int n1 = ((t & 7) << 4) + (L & 15);
    lds[12288 + i] = (__bf16)W1[n1 * 64 + k1];
    // W2: t = kt*4+nt (kt in 0..3, nt in 0..3), W2 is [D=64][2D=128],
    // B-frag B2[k=e][n=d] = W2[d*128+e]
    const int k2 = ((t >> 2) << 5) + ((L >> 4) << 3) + j;
    const int n2 = ((t & 3) << 4) + (L & 15);
    lds[20480 + i] = (__bf16)W2[n2 * 128 + k2];
  }
  __syncthreads();

  // ---- per-lane params (column index = nt*16 + c) ----
  float fgv[4], l1wv[4], l1bv[4], b2v[4], l2wv[8], l2bv[8];
#pragma unroll
  for (int t = 0; t < 4; ++t) {
    fgv[t]  = FG[t * 16 + c];
    l1wv[t] = L1W[t * 16 + c];
    l1bv[t] = L1B[t * 16 + c];
    b2v[t]  = B2g[t * 16 + c];
  }
#pragma unroll
  for (int t = 0; t < 8; ++t) { l2wv[t] = L2W[t * 16 + c]; l2bv[t] = L2B[t * 16 + c]; }

  const f32x4 zf = {0.f, 0.f, 0.f, 0.f};

  for (int it = 0; it < 8; ++it) {
    int lz = 0;
    asm volatile("" : "+s"(lz));          // launder: keep LDS frag loads inside the loop
    const __bf16* wl = lds + lz;
    __bf16* stg = lds + 28672 + wave * 1024 + lz;

    const bf16x8 aq0 = pack8(q0, q1), aq1 = pack8(q2, q3);
    const bf16x8 ak0 = pack8(k0, k1), ak1 = pack8(k2, k3);
    const bf16x8 av0 = pack8(v0, v1), av1 = pack8(v2, v3);

    // software pipeline: issue next-iteration Q/K/V loads into the registers
    // pack8 just freed; their latency hides under this iteration's compute.
    if (it < 7) {
      const int np = pair + 4;
      const float* qn = Qg + np * 1024;
      const float* kn = Kg + np * 1024;
      const float* vn = Vg + np * 1024;
      q0 = *(const f32x4*)(qn + aoff);      q1 = *(const f32x4*)(qn + aoff + 4);
      q2 = *(const f32x4*)(qn + aoff + 32); q3 = *(const f32x4*)(qn + aoff + 36);
      k0 = *(const f32x4*)(kn + aoff);      k1 = *(const f32x4*)(kn + aoff + 4);
      k2 = *(const f32x4*)(kn + aoff + 32); k3 = *(const f32x4*)(kn + aoff + 36);
      v0 = *(const f32x4*)(vn + aoff);      v1 = *(const f32x4*)(vn + aoff + 4);
      v2 = *(const f32x4*)(vn + aoff + 32); v3 = *(const f32x4*)(vn + aoff + 36);
    }

    f32x4 accq[4], acck[4], accv[4];
#pragma unroll
    for (int nt = 0; nt < 4; ++nt) { accq[nt] = zf; acck[nt] = zf; accv[nt] = zf; }

#pragma unroll
    for (int nt = 0; nt < 4; ++nt) {
      accq[nt] = MFMA(aq0, *(const bf16x8*)(wl + nt * 512 + lane * 8), accq[nt]);
      accq[nt] = MFMA(aq1, *(const bf16x8*)(wl + (4 + nt) * 512 + lane * 8), accq[nt]);
      acck[nt] = MFMA(ak0, *(const bf16x8*)(wl + 4096 + nt * 512 + lane * 8), acck[nt]);
      acck[nt] = MFMA(ak1, *(const bf16x8*)(wl + 4096 + (4 + nt) * 512 + lane * 8), acck[nt]);
      accv[nt] = MFMA(av0, *(const bf16x8*)(wl + 8192 + nt * 512 + lane * 8), accv[nt]);
      accv[nt] = MFMA(av1, *(const bf16x8*)(wl + 8192 + (4 + nt) * 512 + lane * 8), accv[nt]);
    }

    // elementwise gated memory (fp32), write cur_mem, form cv
    float cv[4][4];
#pragma unroll
    for (int nt = 0; nt < 4; ++nt) {
      const float f = fgv[nt];
#pragma unroll
      for (int r = 0; r < 4; ++r) {
        const float mm = mv[nt][r];
        const float cell = acck[nt][r] * accv[nt][r] + f * mm;
        const float cm = (1.f - f) * cell + f * mm;
        Cm[mb + (g * 4 + r) * SD + nt * 16] = cm;
        cv[nt][r] = accq[nt][r] * cm;
      }
    }

    // software pipeline: mv/mb now dead for this iteration — prefetch next
    // iteration's memory cells; latency hides under LN1..W2 (~2k cycles).
    if (it < 7) {
      const int np = pair + 4;
      mb = (np >> 12) * HSD + (np & 4095) * 64 + c;
#pragma unroll
      for (int nt = 0; nt < 4; ++nt)
#pragma unroll
        for (int r = 0; r < 4; ++r)
          mv[nt][r] = Mg[mb + (g * 4 + r) * SD + nt * 16];
    }

    // LN1 over 64 (row = 16 lanes x 4 nt-accs at reg r)
    float yv[4][4];
#pragma unroll
    for (int r = 0; r < 4; ++r) {
      float s1 = cv[0][r] + cv[1][r] + cv[2][r] + cv[3][r];
      float s2 = cv[0][r] * cv[0][r] + cv[1][r] * cv[1][r] + cv[2][r] * cv[2][r] + cv[3][r] * cv[3][r];
#pragma unroll
      for (int msk = 1; msk <= 8; msk <<= 1) {
        s1 += __shfl_xor(s1, msk);
        s2 += __shfl_xor(s2, msk);
      }
      const float mu = s1 * 0.015625f;
      const float var = s2 * 0.015625f - mu * mu;
      const float rstd = rsqrtf(var + 1e-5f);
#pragma unroll
      for (int nt = 0; nt < 4; ++nt)
        yv[nt][r] = (cv[nt][r] - mu) * rstd * l1wv[nt] + l1bv[nt];
    }

    // C-layout -> A-layout via swizzled LDS round-trip, then h1 = LN1 @ W1^T
    wave_fence();
#pragma unroll
    for (int nt = 0; nt < 4; ++nt)
#pragma unroll
      for (int r = 0; r < 4; ++r) {
        const int m = g * 4 + r, k = nt * 16 + c;
        stg[(m << 6) + ((((k >> 3) ^ (m & 7)) << 3)) + (k & 7)] = (__bf16)yv[nt][r];
      }
    wave_fence();
    bf16x8 a2[2];
#pragma unroll
    for (int kt = 0; kt < 2; ++kt)
      a2[kt] = *(const bf16x8*)(stg + (c << 6) + ((((kt * 4 + g) ^ (c & 7)) << 3)));

    f32x4 acch[8];
#pragma unroll
    for (int j = 0; j < 8; ++j) acch[j] = zf;
#pragma unroll
    for (int kt = 0; kt < 2; ++kt)
#pragma unroll
      for (int nt = 0; nt < 8; ++nt)
        acch[nt] = MFMA(a2[kt], *(const bf16x8*)(wl + 12288 + (kt * 8 + nt) * 512 + lane * 8), acch[nt]);

    // LN2 over 128
    float zz[8][4];
#pragma unroll
    for (int r = 0; r < 4; ++r) {
      float s1 = 0.f, s2 = 0.f;
#pragma unroll
      for (int j = 0; j < 8; ++j) { const float x = acch[j][r]; s1 += x; s2 += x * x; }
#pragma unroll
      for (int msk = 1; msk <= 8; msk <<= 1) {
        s1 += __shfl_xor(s1, msk);
        s2 += __shfl_xor(s2, msk);
      }
      const float mu = s1 * 0.0078125f;
      const float var = s2 * 0.0078125f - mu * mu;
      const float rstd = rsqrtf(var + 1e-5f);
#pragma unroll
      for (int j = 0; j < 8; ++j)
        zz[j][r] = (acch[j][r] - mu) * rstd * l2wv[j] + l2bv[j];
    }

    // mixed = LN2 @ W2^T (K=128 in two 64-wide halves through the same staging
    // buffer), W2 B-frags from LDS
    f32x4 acco[4];
#pragma unroll
    for (int nt = 0; nt < 4; ++nt) acco[nt] = zf;
#pragma unroll
    for (int half = 0; half < 2; ++half) {
      wave_fence();
#pragma unroll
      for (int jj = 0; jj < 4; ++jj)
#pragma unroll
        for (int r = 0; r < 4; ++r) {
          const int m = g * 4 + r, k = jj * 16 + c;
          stg[(m << 6) + ((((k >> 3) ^ (m & 7)) << 3)) + (k & 7)] = (__bf16)zz[half * 4 + jj][r];
        }
      wave_fence();
#pragma unroll
      for (int kk = 0; kk < 2; ++kk) {
        const bf16x8 a3 = *(const bf16x8*)(stg + (c << 6) + ((((kk * 4 + g) ^ (c & 7)) << 3)));
#pragma unroll
        for (int nt = 0; nt < 4; ++nt)
          acco[nt] = MFMA(a3, *(const bf16x8*)(wl + 20480 + ((half * 2 + kk) * 4 + nt) * 512 + lane * 8), acco[nt]);
      }
    }

    // epilogue: + b2, write out[b][s][h*64+d]
    const int ob = pair * 1024;
#pragma unroll
    for (int nt = 0; nt < 4; ++nt)
#pragma unroll
      for (int r = 0; r < 4; ++r)
        Out[ob + (g * 4 + r) * 64 + nt * 16 + c] = acco[nt][r] + b2v[nt];

    pair += 4;
  }
}

extern "C" void kernel_launch(void* const* d_in, const int* in_sizes, int n_in,
                              void* d_out, int out_size, void* d_ws, size_t ws_size,
                              hipStream_t stream) {
  const float* Qg  = (const float*)d_in[0];
  const float* Kg  = (const float*)d_in[1];
  const float* Vg  = (const float*)d_in[2];
  const float* Mg  = (const float*)d_in[3];
  const float* Wq  = (const float*)d_in[4];
  const float* Wk  = (const float*)d_in[5];
  const float* Wv  = (const float*)d_in[6];
  const float* FG  = (const float*)d_in[7];
  const float* L1W = (const float*)d_in[8];
  const float* L1B = (const float*)d_in[9];
  const float* W1  = (const float*)d_in[10];
  const float* L2W = (const float*)d_in[11];
  const float* L2B = (const float*)d_in[12];
  const float* W2  = (const float*)d_in[13];
  const float* B2g = (const float*)d_in[14];
  float* Out = (float*)d_out;
  float* Cm  = Out + 33554432;  // out is [B,S,HID] then cur_mem [B,H,S,D]

  mixer_kernel<<<dim3(1024), dim3(256), 0, stream>>>(
      Qg, Kg, Vg, Mg, Wq, Wk, Wv, FG, L1W, L1B, W1, L2W, L2B, W2, B2g, Out, Cm);
}